// Round 15
// baseline (8975.348 us; speedup 1.0000x reference)
//
#include <hip/hip_runtime.h>
#include <stdint.h>

// Seq2Seq (bi-LSTM encoder + greedy LSTM decoder), MI355X gfx950.
// v15: v14 with the K-coverage bug fixed (q<64, was q<32 -> summed only
//   half of K -> wrong logits -> argmax divergence, absmax 5.4e-2).
//   Tiling unchanged: kc4/bg16, 1 pass of 8 rows; one h-read pair per q
//   feeds all 8 rows (128 b128/wave, half of v13); w 64B/instr NT
//   (coalescing width proven neutral in R9); acc[8r][2j]=16 regs.
//
// B=32 S=128 T=64 V=32000 E=512 H=512 (4H=2048 gates per cell)

#define NT 1024
#define NBLK 256

constexpr int HSTR = 580;    // enc h-stage LDS row stride (512 + pad, %32==4)
constexpr int XSTR = 1156;   // dec [x|h]-stage stride (1024 + pad, %32==4)
constexpr unsigned LDS_ENC = 78336;    // (32*580 + 512 + 512) floats
constexpr unsigned LDS_CELL = 150016;  // (32*1156 + 512) floats
constexpr unsigned LDS_CLS = 148480;   // cH[32][258]f4 + oL[32][126] + amaxL[32]

// workspace layout (bytes)
constexpr size_t OFF_AMAX  = 0;                     // 63*32 u64 = 16128
constexpr size_t OFF_XG    = 17408;                 // 256*128*32*16 f32 = 67108864
constexpr size_t OFF_HENC  = OFF_XG + 67108864ULL;  // 2buf*2dir*32*512 f32 = 262144
constexpr size_t OFF_HCAT  = OFF_HENC + 262144ULL;  // 2buf*32*1024 f32 = 262144
constexpr size_t OFF_CST   = OFF_HCAT + 262144ULL;  // 2dir*32*512 f32 = 131072

typedef float f32x4 __attribute__((ext_vector_type(4)));

__device__ __forceinline__ float sigm(float x) {
  if (x >= 0.f) return 1.f / (1.f + expf(-x));
  float e = expf(x);
  return e / (1.f + e);
}

__device__ __forceinline__ void fma4(const float4& w, const float4& h, float4& a) {
  a.x = fmaf(w.x, h.x, a.x);
  a.y = fmaf(w.y, h.y, a.y);
  a.z = fmaf(w.z, h.z, a.z);
  a.w = fmaf(w.w, h.w, a.w);
}

__device__ __forceinline__ float hsum4(const float4& a) {
  return (a.x + a.y) + (a.z + a.w);
}

__device__ __forceinline__ float dot4(const float4& w, const float4& h, float acc) {
  return fmaf(w.x, h.x, fmaf(w.y, h.y, fmaf(w.z, h.z, fmaf(w.w, h.w, acc))));
}

__device__ __forceinline__ float dot4v(const f32x4& w, const float4& h, float acc) {
  return fmaf(w.x, h.x, fmaf(w.y, h.y, fmaf(w.z, h.z, fmaf(w.w, h.w, acc))));
}

__device__ __forceinline__ unsigned long long lgkey(float lg, int vr) {
  unsigned u = __float_as_uint(lg);
  u = (u & 0x80000000u) ? ~u : (u | 0x80000000u);
  return ((unsigned long long)u << 32) | (0xFFFFFFFFu - (unsigned)vr);
}

// ---------------- K0: Xg = emb(src) @ wih^T + bih + bhh; init h_enc, out ----
__global__ __launch_bounds__(NT) void k_xg(
    const int* __restrict__ src, const float* __restrict__ enc_emb,
    const float* __restrict__ ewih_f, const float* __restrict__ ebih_f,
    const float* __restrict__ ebhh_f,
    const float* __restrict__ ewih_r, const float* __restrict__ ebih_r,
    const float* __restrict__ ebhh_r,
    float* __restrict__ Xg, float* __restrict__ h_enc, float* __restrict__ out) {
  extern __shared__ float smem[];
  const int tid = threadIdx.x;
  const int bid = blockIdx.x;
  const int d  = bid >> 7;
  const int u0 = (bid & 127) << 2;

  float* hL  = smem;               // [32][HSTR]

  const int rgE = tid >> 7;
  const int bpE = (tid >> 4) & 7;
  const int ksE = tid & 15;
  const int r0E = rgE * 2, r1E = r0E + 1;
  const int growE0 = (r0E & 3) * 512 + u0 + (r0E >> 2);
  const int growE1 = (r1E & 3) * 512 + u0 + (r1E >> 2);

  const float* ewih = d ? ewih_r : ewih_f;
  const float* ebih = d ? ebih_r : ebih_f;
  const float* ebhh = d ? ebhh_r : ebhh_f;

  float4 wA[8], wB[8];
#pragma unroll
  for (int i4 = 0; i4 < 8; ++i4) {
    wA[i4] = *(const float4*)(ewih + (size_t)growE0 * 512 + ksE * 32 + i4 * 4);
    wB[i4] = *(const float4*)(ewih + (size_t)growE1 * 512 + ksE * 32 + i4 * 4);
  }
  const float biasA = ebih[growE0] + ebhh[growE0];
  const float biasB = ebih[growE1] + ebhh[growE1];

  for (int t = 0; t < 128; ++t) {
    {
      int b = tid >> 5, i = tid & 31;
      int tok = src[b * 128 + t];
      const float* row = enc_emb + (size_t)tok * 512;
#pragma unroll
      for (int q = 0; q < 4; ++q) {
        int k = (i + 32 * q) * 4;
        float4 v = *(const float4*)(row + k);
        int pc = k + ((k >> 5) << 2);
        *(float4*)(hL + b * HSTR + pc) = v;
      }
    }
    __syncthreads();
    for (int gi = 0; gi < 4; ++gi) {
      int b = bpE * 4 + gi;
      const float* hb = hL + b * HSTR + ksE * 36;
      float4 a0 = {0, 0, 0, 0}, a1 = {0, 0, 0, 0};
#pragma unroll
      for (int i4 = 0; i4 < 8; ++i4) {
        float4 h4 = *(const float4*)(hb + i4 * 4);
        fma4(wA[i4], h4, a0);
        fma4(wB[i4], h4, a1);
      }
      float s0 = hsum4(a0), s1 = hsum4(a1);
#pragma unroll
      for (int m = 1; m <= 8; m <<= 1) {
        s0 += __shfl_xor(s0, m, 64);
        s1 += __shfl_xor(s1, m, 64);
      }
      if (ksE == 0) {
        float* xgp = Xg + ((size_t)bid << 16) + t * 512 + b * 16;
        xgp[r0E] = s0 + biasA;
        xgp[r1E] = s1 + biasB;
      }
    }
    __syncthreads();
  }

  if (tid < 128) {
    int b = tid & 31, j = tid >> 5;
    h_enc[((0 * 2 + d) * 32 + b) * 512 + u0 + j] = 0.f;
  }
  for (int i = tid; i < 4000; i += NT) {
    int b = i & 31, vv = i >> 5;  // vv < 125
    __builtin_nontemporal_store(0.f,
        &out[(size_t)b * 64 * 32000 + bid * 125 + vv]);
  }
}

// ---------------- K_enc: one bi-LSTM encoder time step ----------------
__global__ __launch_bounds__(NT) void k_enc(
    const float* __restrict__ ewhh_f, const float* __restrict__ ewhh_r,
    const float* __restrict__ Xg, float* __restrict__ h_enc,
    float* __restrict__ hcat, float* __restrict__ c_st, int s) {
  extern __shared__ float smem[];
  const int tid = threadIdx.x;
  const int bid = blockIdx.x;
  const int d  = bid >> 7;
  const int u0 = (bid & 127) << 2;
  const int cur = s & 1;
  const int td = d ? (127 - s) : s;

  float* hL  = smem;               // [32][HSTR]
  float* XgL = smem + 32 * HSTR;   // [32*16]
  float* gL  = XgL + 512;          // [32*16]

  const int rgE = tid >> 7;
  const int bpE = (tid >> 4) & 7;
  const int ksE = tid & 15;
  const int r0E = rgE * 2, r1E = r0E + 1;
  const int growE0 = (r0E & 3) * 512 + u0 + (r0E >> 2);
  const int growE1 = (r1E & 3) * 512 + u0 + (r1E >> 2);

  const float* ewhh = d ? ewhh_r : ewhh_f;

  float4 wA[8], wB[8];
#pragma unroll
  for (int i4 = 0; i4 < 8; ++i4) {
    wA[i4] = *(const float4*)(ewhh + (size_t)growE0 * 512 + ksE * 32 + i4 * 4);
    wB[i4] = *(const float4*)(ewhh + (size_t)growE1 * 512 + ksE * 32 + i4 * 4);
  }

  {
    int b = tid >> 5, i = tid & 31;
    const float* hr = h_enc + ((size_t)(cur * 2 + d) * 32 + b) * 512;
#pragma unroll
    for (int q = 0; q < 4; ++q) {
      int k = (i + 32 * q) * 4;
      float4 v = *(const float4*)(hr + k);
      int pc = k + ((k >> 5) << 2);
      *(float4*)(hL + b * HSTR + pc) = v;
    }
    if (tid < 128) {
      ((float4*)XgL)[tid] =
          *(const float4*)(Xg + ((size_t)bid << 16) + td * 512 + tid * 4);
    }
  }
  __syncthreads();
  for (int gi = 0; gi < 4; ++gi) {
    int b = bpE * 4 + gi;
    const float* hb = hL + b * HSTR + ksE * 36;
    float4 a0 = {0, 0, 0, 0}, a1 = {0, 0, 0, 0};
#pragma unroll
    for (int i4 = 0; i4 < 8; ++i4) {
      float4 h4 = *(const float4*)(hb + i4 * 4);
      fma4(wA[i4], h4, a0);
      fma4(wB[i4], h4, a1);
    }
    float s0 = hsum4(a0), s1 = hsum4(a1);
#pragma unroll
    for (int m = 1; m <= 8; m <<= 1) {
      s0 += __shfl_xor(s0, m, 64);
      s1 += __shfl_xor(s1, m, 64);
    }
    if (ksE == 0) {
      gL[b * 16 + r0E] = s0 + XgL[b * 16 + r0E];
      gL[b * 16 + r1E] = s1 + XgL[b * 16 + r1E];
    }
  }
  __syncthreads();
  if (tid < 128) {
    int b = tid & 31, j = tid >> 5;
    float g_i = gL[b * 16 + (j << 2) + 0];
    float g_f = gL[b * 16 + (j << 2) + 1];
    float g_g = gL[b * 16 + (j << 2) + 2];
    float g_o = gL[b * 16 + (j << 2) + 3];
    float c = (s == 0) ? 0.f : c_st[(d * 32 + b) * 512 + u0 + j];
    c = sigm(g_f) * c + sigm(g_i) * tanhf(g_g);
    float h = sigm(g_o) * tanhf(c);
    c_st[(d * 32 + b) * 512 + u0 + j] = c;
    h_enc[(((cur ^ 1) * 2 + d) * 32 + b) * 512 + u0 + j] = h;
    if (s == 127) hcat[b * 1024 + d * 512 + u0 + j] = h;  // buf 0
  }
}

// ---------------- K_cell: one decoder LSTM step (both dirs) ----------------
__global__ __launch_bounds__(NT) void k_cell(
    const int* __restrict__ tgt, const float* __restrict__ dec_emb,
    const float* __restrict__ dwih_f, const float* __restrict__ dwhh_f,
    const float* __restrict__ dbih_f, const float* __restrict__ dbhh_f,
    const float* __restrict__ dwih_r, const float* __restrict__ dwhh_r,
    const float* __restrict__ dbih_r, const float* __restrict__ dbhh_r,
    float* __restrict__ hcat, float* __restrict__ c_st,
    const unsigned long long* __restrict__ amax, int t) {
  extern __shared__ float smem[];
  const int tid = threadIdx.x;
  const int bid = blockIdx.x;
  const int d  = bid >> 7;
  const int u0 = (bid & 127) << 2;
  const int p = t & 1;

  float* xhL = smem;               // [32][XSTR]
  float* gLd = smem + 32 * XSTR;   // [32*16]

  const int rgD = tid >> 7;
  const int bpD = (tid >> 5) & 3;
  const int ksD = tid & 31;
  const int r0D = rgD * 2, r1D = r0D + 1;
  const int growD0 = (r0D & 3) * 512 + u0 + (r0D >> 2);
  const int growD1 = (r1D & 3) * 512 + u0 + (r1D >> 2);

  const float* dwih = d ? dwih_r : dwih_f;
  const float* dwhh = d ? dwhh_r : dwhh_f;
  const float* dbih = d ? dbih_r : dbih_f;
  const float* dbhh = d ? dbhh_r : dbhh_f;

  {
    int b = tid >> 5, i = tid & 31;
    int tok;
    if (t == 0) {
      tok = tgt[b * 64];
    } else {
      unsigned long long kv = amax[(t - 1) * 32 + b];
      tok = (int)(0xFFFFFFFFu - (unsigned)(kv & 0xFFFFFFFFull));
    }
    const float* xr = dec_emb + (size_t)tok * 512;
    const float* hr = hcat + (size_t)p * 32768 + b * 1024 + d * 512;
#pragma unroll
    for (int q = 0; q < 4; ++q) {
      int k = (i + 32 * q) * 4;
      float4 v = *(const float4*)(xr + k);
      int pc = k + ((k >> 5) << 2);
      *(float4*)(xhL + b * XSTR + pc) = v;
    }
#pragma unroll
    for (int q = 0; q < 4; ++q) {
      int k = (i + 32 * q) * 4;
      float4 v = *(const float4*)(hr + k);
      int c2 = 512 + k;
      int pc = c2 + ((c2 >> 5) << 2);
      *(float4*)(xhL + b * XSTR + pc) = v;
    }
  }
  float4 wA[8], wB[8];
  {
    const float* s0p = (ksD < 16) ? (dwih + (size_t)growD0 * 512 + ksD * 32)
                                  : (dwhh + (size_t)growD0 * 512 + (ksD - 16) * 32);
    const float* s1p = (ksD < 16) ? (dwih + (size_t)growD1 * 512 + ksD * 32)
                                  : (dwhh + (size_t)growD1 * 512 + (ksD - 16) * 32);
#pragma unroll
    for (int i4 = 0; i4 < 8; ++i4) {
      wA[i4] = *(const float4*)(s0p + i4 * 4);
      wB[i4] = *(const float4*)(s1p + i4 * 4);
    }
  }
  const float biasA = dbih[growD0] + dbhh[growD0];
  const float biasB = dbih[growD1] + dbhh[growD1];
  __syncthreads();
  for (int gi = 0; gi < 8; ++gi) {
    int b = bpD * 8 + gi;
    const float* hb = xhL + b * XSTR + ksD * 36;
    float4 a0 = {0, 0, 0, 0}, a1 = {0, 0, 0, 0};
#pragma unroll
    for (int i4 = 0; i4 < 8; ++i4) {
      float4 h4 = *(const float4*)(hb + i4 * 4);
      fma4(wA[i4], h4, a0);
      fma4(wB[i4], h4, a1);
    }
    float s0 = hsum4(a0), s1 = hsum4(a1);
#pragma unroll
    for (int m = 1; m <= 16; m <<= 1) {
      s0 += __shfl_xor(s0, m, 64);
      s1 += __shfl_xor(s1, m, 64);
    }
    if (ksD == 0) {
      gLd[b * 16 + r0D] = s0 + biasA;
      gLd[b * 16 + r1D] = s1 + biasB;
    }
  }
  __syncthreads();
  if (tid < 128) {
    int b = tid & 31, j = tid >> 5;
    float g_i = gLd[b * 16 + (j << 2) + 0];
    float g_f = gLd[b * 16 + (j << 2) + 1];
    float g_g = gLd[b * 16 + (j << 2) + 2];
    float g_o = gLd[b * 16 + (j << 2) + 3];
    float c = c_st[(d * 32 + b) * 512 + u0 + j];
    c = sigm(g_f) * c + sigm(g_i) * tanhf(g_g);
    float h = sigm(g_o) * tanhf(c);
    c_st[(d * 32 + b) * 512 + u0 + j] = c;
    hcat[(size_t)(p ^ 1) * 32768 + b * 1024 + d * 512 + u0 + j] = h;
  }
}

// ---------------- K_cls v15: kc4/bg16, 1 pass of 8 rows, q<64 ----------------
// grid 256 (one block per row-group: 125 rows x 32 b x full K).
// lane = (bg[0,16) x kc[0,4)): lane's batches b = bg, bg+16 (j=2). One
// h-read pair per q feeds all 8 rows (128 b128/wave); w in 2 groups of 4.
// q<64 covers K=1024 (floats q*16 + kc*4). acc[8r][2j]=16 regs;
// kc-butterfly(1,2) = allreduce; lane kc keeps rows kc and kc+4.
__global__ __launch_bounds__(NT) void k_cls(
    const float* __restrict__ cls_w, const float* __restrict__ cls_b,
    const float* __restrict__ hcat, unsigned long long* __restrict__ amax,
    float* __restrict__ out, int t) {
  extern __shared__ float smem[];
  const int tid = threadIdx.x;
  const int g = blockIdx.x;
  const int p = t & 1;

  // LDS: cH float4[32][258] floats [0,33024); oL [32][126] floats [33024,37056);
  //      amaxL u64[32] at float 37056 (bytes 148224..148480)
  float* oL = smem + 33024;
  unsigned long long* amaxL = (unsigned long long*)(smem + 37056);

  {  // stage full h into padded cH; zero amaxL
    const float4* hr4 = (const float4*)(hcat + (size_t)(p ^ 1) * 32768);
    float4* cH4w = (float4*)smem;
#pragma unroll
    for (int q = 0; q < 8; ++q) {
      int f = tid + q * 1024;        // [0,8192)
      int b = f >> 8, k4 = f & 255;
      cH4w[b * 258 + k4] = hr4[f];
    }
    if (tid < 32) amaxL[tid] = 0ull;
  }
  __syncthreads();
  {
    const int lane = tid & 63;
    const int widu = __builtin_amdgcn_readfirstlane(tid >> 6);
    const int kc = lane & 3;          // k-chunk [0,4): 64B coalesced w-loads
    const int bg = lane >> 2;         // batch-class [0,16): b = bg, bg+16
    const float4* cH4 = (const float4*)smem;

    const int lr0 = widu * 8;
    const float* wr[8];
#pragma unroll
    for (int r = 0; r < 8; ++r) {
      int lr = lr0 + r;
      lr = lr > 124 ? 124 : lr;      // rows 125..127 clamped (stores guarded)
      wr[r] = cls_w + (size_t)(g * 125 + lr) * 1024;
    }

    float acc[16];   // acc[r*2 + j]
#pragma unroll
    for (int i = 0; i < 16; ++i) acc[i] = 0.f;

    const float4* hp0 = cH4 + bg * 258 + kc;
    const float4* hp1 = cH4 + (bg + 16) * 258 + kc;
#pragma unroll 2
    for (int q = 0; q < 64; ++q) {   // q<64: covers K floats [0,1024)
      const int ko = q * 16 + kc * 4;      // 4 kc lanes cover 64B contiguous
      // group 1: rows 0..3
      f32x4 w0 = __builtin_nontemporal_load((const f32x4*)(wr[0] + ko));
      f32x4 w1 = __builtin_nontemporal_load((const f32x4*)(wr[1] + ko));
      f32x4 w2 = __builtin_nontemporal_load((const f32x4*)(wr[2] + ko));
      f32x4 w3 = __builtin_nontemporal_load((const f32x4*)(wr[3] + ko));
      float4 h0 = hp0[q * 4];
      float4 h1 = hp1[q * 4];
      acc[0] = dot4v(w0, h0, acc[0]);  acc[1] = dot4v(w0, h1, acc[1]);
      acc[2] = dot4v(w1, h0, acc[2]);  acc[3] = dot4v(w1, h1, acc[3]);
      acc[4] = dot4v(w2, h0, acc[4]);  acc[5] = dot4v(w2, h1, acc[5]);
      acc[6] = dot4v(w3, h0, acc[6]);  acc[7] = dot4v(w3, h1, acc[7]);
      // group 2: rows 4..7 (same h, still live)
      f32x4 w4 = __builtin_nontemporal_load((const f32x4*)(wr[4] + ko));
      f32x4 w5 = __builtin_nontemporal_load((const f32x4*)(wr[5] + ko));
      f32x4 w6 = __builtin_nontemporal_load((const f32x4*)(wr[6] + ko));
      f32x4 w7 = __builtin_nontemporal_load((const f32x4*)(wr[7] + ko));
      acc[8]  = dot4v(w4, h0, acc[8]);   acc[9]  = dot4v(w4, h1, acc[9]);
      acc[10] = dot4v(w5, h0, acc[10]);  acc[11] = dot4v(w5, h1, acc[11]);
      acc[12] = dot4v(w6, h0, acc[12]);  acc[13] = dot4v(w6, h1, acc[13]);
      acc[14] = dot4v(w7, h0, acc[14]);  acc[15] = dot4v(w7, h1, acc[15]);
    }

    // butterfly over the 4 kc lanes = allreduce (every lane gets full sums)
#pragma unroll
    for (int i = 0; i < 16; ++i) {
      acc[i] += __shfl_xor(acc[i], 1, 64);
      acc[i] += __shfl_xor(acc[i], 2, 64);
    }

    // static select: lane kc keeps rows rA=kc and rB=kc+4 (acc idx r*2+j)
    float sA0, sA1, sB0, sB1;
    {
      float t0 = (kc & 1) ? acc[2]  : acc[0];
      float t1 = (kc & 1) ? acc[6]  : acc[4];
      sA0 = (kc & 2) ? t1 : t0;
      float u0 = (kc & 1) ? acc[3]  : acc[1];
      float u1 = (kc & 1) ? acc[7]  : acc[5];
      sA1 = (kc & 2) ? u1 : u0;
      float v0 = (kc & 1) ? acc[10] : acc[8];
      float v1 = (kc & 1) ? acc[14] : acc[12];
      sB0 = (kc & 2) ? v1 : v0;
      float w0 = (kc & 1) ? acc[11] : acc[9];
      float w1 = (kc & 1) ? acc[15] : acc[13];
      sB1 = (kc & 2) ? w1 : w0;
    }

    const int lrA = lr0 + kc;            // <= 123, always valid
    const int lrB = lrA + 4;             // up to 127; >=125 invalid
    const int lrBc = lrB > 124 ? 124 : lrB;
    const int vrA = g * 125 + lrA;
    const int vrB = g * 125 + lrBc;
    const float cbA = cls_b[vrA];
    const float cbB = cls_b[vrB];
    const float lgA0 = sA0 + cbA, lgA1 = sA1 + cbA;   // rows lrA, b = bg / bg+16
    const float lgB0 = sB0 + cbB, lgB1 = sB1 + cbB;   // rows lrB

    oL[bg * 126 + lrA] = lgA0;
    oL[(bg + 16) * 126 + lrA] = lgA1;
    unsigned long long k0 = lgkey(lgA0, vrA);
    unsigned long long k1 = lgkey(lgA1, vrA);
    if (lrB < 125) {
      oL[bg * 126 + lrB] = lgB0;
      oL[(bg + 16) * 126 + lrB] = lgB1;
      unsigned long long kB0 = lgkey(lgB0, vrB);
      unsigned long long kB1 = lgkey(lgB1, vrB);
      k0 = kB0 > k0 ? kB0 : k0;
      k1 = kB1 > k1 ? kB1 : k1;
    }
    // max over the 4 kc lanes for each batch
#pragma unroll
    for (int m = 1; m <= 2; m <<= 1) {
      unsigned long long o0 = __shfl_xor(k0, m, 64);
      unsigned long long o1 = __shfl_xor(k1, m, 64);
      k0 = o0 > k0 ? o0 : k0;
      k1 = o1 > k1 ? o1 : k1;
    }
    if (kc == 0) {
      atomicMax(&amaxL[bg], k0);
      atomicMax(&amaxL[bg + 16], k1);
    }
  }
  __syncthreads();
  // coalesced logit writeback (non-temporal) + global argmax merge
#pragma unroll
  for (int it = 0; it < 4; ++it) {
    int idx = tid + it * 1024;            // [0,4096)
    int b = idx >> 7, j = idx & 127;
    if (j < 125)
      __builtin_nontemporal_store(oL[b * 126 + j],
          &out[((size_t)b * 64 + (t + 1)) * 32000 + g * 125 + j]);
  }
  if (tid < 32) atomicMax(&amax[t * 32 + tid], amaxL[tid]);
}

extern "C" void kernel_launch(void* const* d_in, const int* in_sizes, int n_in,
                              void* d_out, int out_size, void* d_ws, size_t ws_size,
                              hipStream_t stream) {
  (void)in_sizes; (void)n_in; (void)out_size; (void)ws_size;
  const int*   src     = (const int*)d_in[0];
  const int*   tgt     = (const int*)d_in[1];
  const float* enc_emb = (const float*)d_in[2];
  const float* dec_emb = (const float*)d_in[3];
  const float* ewih_f  = (const float*)d_in[4];
  const float* ewhh_f  = (const float*)d_in[5];
  const float* ebih_f  = (const float*)d_in[6];
  const float* ebhh_f  = (const float*)d_in[7];
  const float* ewih_r  = (const float*)d_in[8];
  const float* ewhh_r  = (const float*)d_in[9];
  const float* ebih_r  = (const float*)d_in[10];
  const float* ebhh_r  = (const float*)d_in[11];
  const float* dwih_f  = (const float*)d_in[12];
  const float* dwhh_f  = (const float*)d_in[13];
  const float* dbih_f  = (const float*)d_in[14];
  const float* dbhh_f  = (const float*)d_in[15];
  const float* dwih_r  = (const float*)d_in[16];
  const float* dwhh_r  = (const float*)d_in[17];
  const float* dbih_r  = (const float*)d_in[18];
  const float* dbhh_r  = (const float*)d_in[19];
  const float* cls_w   = (const float*)d_in[20];
  const float* cls_b   = (const float*)d_in[21];

  char* ws = (char*)d_ws;
  unsigned long long* amax = (unsigned long long*)(ws + OFF_AMAX);
  float* Xg                = (float*)(ws + OFF_XG);
  float* h_enc             = (float*)(ws + OFF_HENC);
  float* hcat              = (float*)(ws + OFF_HCAT);
  float* c_st              = (float*)(ws + OFF_CST);
  float* out               = (float*)d_out;

  // reset argmax slots (monotone atomicMax needs zeros each call)
  hipMemsetAsync(d_ws, 0, OFF_XG, stream);

  hipFuncSetAttribute((const void*)k_xg,
                      hipFuncAttributeMaxDynamicSharedMemorySize, LDS_ENC);
  hipFuncSetAttribute((const void*)k_enc,
                      hipFuncAttributeMaxDynamicSharedMemorySize, LDS_ENC);
  hipFuncSetAttribute((const void*)k_cell,
                      hipFuncAttributeMaxDynamicSharedMemorySize, LDS_CELL);
  hipFuncSetAttribute((const void*)k_cls,
                      hipFuncAttributeMaxDynamicSharedMemorySize, LDS_CLS);

  hipLaunchKernelGGL(k_xg, dim3(NBLK), dim3(NT), LDS_ENC, stream,
                     src, enc_emb, ewih_f, ebih_f, ebhh_f,
                     ewih_r, ebih_r, ebhh_r, Xg, h_enc, out);

  for (int s = 0; s < 128; ++s) {
    hipLaunchKernelGGL(k_enc, dim3(NBLK), dim3(NT), LDS_ENC, stream,
                       ewhh_f, ewhh_r, Xg, h_enc, hcat, c_st, s);
  }

  for (int t = 0; t < 63; ++t) {
    hipLaunchKernelGGL(k_cell, dim3(NBLK), dim3(NT), LDS_CELL, stream,
                       tgt, dec_emb,
                       dwih_f, dwhh_f, dbih_f, dbhh_f,
                       dwih_r, dwhh_r, dbih_r, dbhh_r,
                       hcat, c_st, amax, t);
    hipLaunchKernelGGL(k_cls, dim3(NBLK), dim3(NT), LDS_CLS, stream,
                       cls_w, cls_b, hcat, amax, out, t);
  }
}

// Round 16
// 7069.290 us; speedup vs baseline: 1.2696x; 1.2696x over previous
//
#include <hip/hip_runtime.h>
#include <stdint.h>

// Seq2Seq (bi-LSTM encoder + greedy LSTM decoder), MI355X gfx950.
// v16: revert k_cls to v13 (kc8/bg8, 2 passes — the empirical optimum:
//   v12 256B/4xLDS=7.40, v13 128B/2xLDS=7.09, v15 64B/1xLDS=8.98 => the
//   coalescing-vs-LDS tradeoff peaks at 128B) + deepen the MLP: q-loop
//   unroll 2->4 (~8 -> ~16 NT loads in flight/lane; Little's law at 900ns
//   HBM latency: 4.6 -> >6.3 TB/s ceiling). Live set ~55 < 64 VGPR.
//   k_xg / k_enc / k_cell byte-identical to v13.
//
// B=32 S=128 T=64 V=32000 E=512 H=512 (4H=2048 gates per cell)

#define NT 1024
#define NBLK 256

constexpr int HSTR = 580;    // enc h-stage LDS row stride (512 + pad, %32==4)
constexpr int XSTR = 1156;   // dec [x|h]-stage stride (1024 + pad, %32==4)
constexpr unsigned LDS_ENC = 78336;    // (32*580 + 512 + 512) floats
constexpr unsigned LDS_CELL = 150016;  // (32*1156 + 512) floats
constexpr unsigned LDS_CLS = 147968;   // cH[32][257]f4 + oL[32][126] + amaxL[32]

// workspace layout (bytes)
constexpr size_t OFF_AMAX  = 0;                     // 63*32 u64 = 16128
constexpr size_t OFF_XG    = 17408;                 // 256*128*32*16 f32 = 67108864
constexpr size_t OFF_HENC  = OFF_XG + 67108864ULL;  // 2buf*2dir*32*512 f32 = 262144
constexpr size_t OFF_HCAT  = OFF_HENC + 262144ULL;  // 2buf*32*1024 f32 = 262144
constexpr size_t OFF_CST   = OFF_HCAT + 262144ULL;  // 2dir*32*512 f32 = 131072

typedef float f32x4 __attribute__((ext_vector_type(4)));

__device__ __forceinline__ float sigm(float x) {
  if (x >= 0.f) return 1.f / (1.f + expf(-x));
  float e = expf(x);
  return e / (1.f + e);
}

__device__ __forceinline__ void fma4(const float4& w, const float4& h, float4& a) {
  a.x = fmaf(w.x, h.x, a.x);
  a.y = fmaf(w.y, h.y, a.y);
  a.z = fmaf(w.z, h.z, a.z);
  a.w = fmaf(w.w, h.w, a.w);
}

__device__ __forceinline__ float hsum4(const float4& a) {
  return (a.x + a.y) + (a.z + a.w);
}

__device__ __forceinline__ float dot4(const float4& w, const float4& h, float acc) {
  return fmaf(w.x, h.x, fmaf(w.y, h.y, fmaf(w.z, h.z, fmaf(w.w, h.w, acc))));
}

__device__ __forceinline__ float dot4v(const f32x4& w, const float4& h, float acc) {
  return fmaf(w.x, h.x, fmaf(w.y, h.y, fmaf(w.z, h.z, fmaf(w.w, h.w, acc))));
}

__device__ __forceinline__ unsigned long long lgkey(float lg, int vr) {
  unsigned u = __float_as_uint(lg);
  u = (u & 0x80000000u) ? ~u : (u | 0x80000000u);
  return ((unsigned long long)u << 32) | (0xFFFFFFFFu - (unsigned)vr);
}

// ---------------- K0: Xg = emb(src) @ wih^T + bih + bhh; init h_enc, out ----
__global__ __launch_bounds__(NT) void k_xg(
    const int* __restrict__ src, const float* __restrict__ enc_emb,
    const float* __restrict__ ewih_f, const float* __restrict__ ebih_f,
    const float* __restrict__ ebhh_f,
    const float* __restrict__ ewih_r, const float* __restrict__ ebih_r,
    const float* __restrict__ ebhh_r,
    float* __restrict__ Xg, float* __restrict__ h_enc, float* __restrict__ out) {
  extern __shared__ float smem[];
  const int tid = threadIdx.x;
  const int bid = blockIdx.x;
  const int d  = bid >> 7;
  const int u0 = (bid & 127) << 2;

  float* hL  = smem;               // [32][HSTR]

  const int rgE = tid >> 7;
  const int bpE = (tid >> 4) & 7;
  const int ksE = tid & 15;
  const int r0E = rgE * 2, r1E = r0E + 1;
  const int growE0 = (r0E & 3) * 512 + u0 + (r0E >> 2);
  const int growE1 = (r1E & 3) * 512 + u0 + (r1E >> 2);

  const float* ewih = d ? ewih_r : ewih_f;
  const float* ebih = d ? ebih_r : ebih_f;
  const float* ebhh = d ? ebhh_r : ebhh_f;

  float4 wA[8], wB[8];
#pragma unroll
  for (int i4 = 0; i4 < 8; ++i4) {
    wA[i4] = *(const float4*)(ewih + (size_t)growE0 * 512 + ksE * 32 + i4 * 4);
    wB[i4] = *(const float4*)(ewih + (size_t)growE1 * 512 + ksE * 32 + i4 * 4);
  }
  const float biasA = ebih[growE0] + ebhh[growE0];
  const float biasB = ebih[growE1] + ebhh[growE1];

  for (int t = 0; t < 128; ++t) {
    {
      int b = tid >> 5, i = tid & 31;
      int tok = src[b * 128 + t];
      const float* row = enc_emb + (size_t)tok * 512;
#pragma unroll
      for (int q = 0; q < 4; ++q) {
        int k = (i + 32 * q) * 4;
        float4 v = *(const float4*)(row + k);
        int pc = k + ((k >> 5) << 2);
        *(float4*)(hL + b * HSTR + pc) = v;
      }
    }
    __syncthreads();
    for (int gi = 0; gi < 4; ++gi) {
      int b = bpE * 4 + gi;
      const float* hb = hL + b * HSTR + ksE * 36;
      float4 a0 = {0, 0, 0, 0}, a1 = {0, 0, 0, 0};
#pragma unroll
      for (int i4 = 0; i4 < 8; ++i4) {
        float4 h4 = *(const float4*)(hb + i4 * 4);
        fma4(wA[i4], h4, a0);
        fma4(wB[i4], h4, a1);
      }
      float s0 = hsum4(a0), s1 = hsum4(a1);
#pragma unroll
      for (int m = 1; m <= 8; m <<= 1) {
        s0 += __shfl_xor(s0, m, 64);
        s1 += __shfl_xor(s1, m, 64);
      }
      if (ksE == 0) {
        float* xgp = Xg + ((size_t)bid << 16) + t * 512 + b * 16;
        xgp[r0E] = s0 + biasA;
        xgp[r1E] = s1 + biasB;
      }
    }
    __syncthreads();
  }

  if (tid < 128) {
    int b = tid & 31, j = tid >> 5;
    h_enc[((0 * 2 + d) * 32 + b) * 512 + u0 + j] = 0.f;
  }
  for (int i = tid; i < 4000; i += NT) {
    int b = i & 31, vv = i >> 5;  // vv < 125
    __builtin_nontemporal_store(0.f,
        &out[(size_t)b * 64 * 32000 + bid * 125 + vv]);
  }
}

// ---------------- K_enc: one bi-LSTM encoder time step ----------------
__global__ __launch_bounds__(NT) void k_enc(
    const float* __restrict__ ewhh_f, const float* __restrict__ ewhh_r,
    const float* __restrict__ Xg, float* __restrict__ h_enc,
    float* __restrict__ hcat, float* __restrict__ c_st, int s) {
  extern __shared__ float smem[];
  const int tid = threadIdx.x;
  const int bid = blockIdx.x;
  const int d  = bid >> 7;
  const int u0 = (bid & 127) << 2;
  const int cur = s & 1;
  const int td = d ? (127 - s) : s;

  float* hL  = smem;               // [32][HSTR]
  float* XgL = smem + 32 * HSTR;   // [32*16]
  float* gL  = XgL + 512;          // [32*16]

  const int rgE = tid >> 7;
  const int bpE = (tid >> 4) & 7;
  const int ksE = tid & 15;
  const int r0E = rgE * 2, r1E = r0E + 1;
  const int growE0 = (r0E & 3) * 512 + u0 + (r0E >> 2);
  const int growE1 = (r1E & 3) * 512 + u0 + (r1E >> 2);

  const float* ewhh = d ? ewhh_r : ewhh_f;

  float4 wA[8], wB[8];
#pragma unroll
  for (int i4 = 0; i4 < 8; ++i4) {
    wA[i4] = *(const float4*)(ewhh + (size_t)growE0 * 512 + ksE * 32 + i4 * 4);
    wB[i4] = *(const float4*)(ewhh + (size_t)growE1 * 512 + ksE * 32 + i4 * 4);
  }

  {
    int b = tid >> 5, i = tid & 31;
    const float* hr = h_enc + ((size_t)(cur * 2 + d) * 32 + b) * 512;
#pragma unroll
    for (int q = 0; q < 4; ++q) {
      int k = (i + 32 * q) * 4;
      float4 v = *(const float4*)(hr + k);
      int pc = k + ((k >> 5) << 2);
      *(float4*)(hL + b * HSTR + pc) = v;
    }
    if (tid < 128) {
      ((float4*)XgL)[tid] =
          *(const float4*)(Xg + ((size_t)bid << 16) + td * 512 + tid * 4);
    }
  }
  __syncthreads();
  for (int gi = 0; gi < 4; ++gi) {
    int b = bpE * 4 + gi;
    const float* hb = hL + b * HSTR + ksE * 36;
    float4 a0 = {0, 0, 0, 0}, a1 = {0, 0, 0, 0};
#pragma unroll
    for (int i4 = 0; i4 < 8; ++i4) {
      float4 h4 = *(const float4*)(hb + i4 * 4);
      fma4(wA[i4], h4, a0);
      fma4(wB[i4], h4, a1);
    }
    float s0 = hsum4(a0), s1 = hsum4(a1);
#pragma unroll
    for (int m = 1; m <= 8; m <<= 1) {
      s0 += __shfl_xor(s0, m, 64);
      s1 += __shfl_xor(s1, m, 64);
    }
    if (ksE == 0) {
      gL[b * 16 + r0E] = s0 + XgL[b * 16 + r0E];
      gL[b * 16 + r1E] = s1 + XgL[b * 16 + r1E];
    }
  }
  __syncthreads();
  if (tid < 128) {
    int b = tid & 31, j = tid >> 5;
    float g_i = gL[b * 16 + (j << 2) + 0];
    float g_f = gL[b * 16 + (j << 2) + 1];
    float g_g = gL[b * 16 + (j << 2) + 2];
    float g_o = gL[b * 16 + (j << 2) + 3];
    float c = (s == 0) ? 0.f : c_st[(d * 32 + b) * 512 + u0 + j];
    c = sigm(g_f) * c + sigm(g_i) * tanhf(g_g);
    float h = sigm(g_o) * tanhf(c);
    c_st[(d * 32 + b) * 512 + u0 + j] = c;
    h_enc[(((cur ^ 1) * 2 + d) * 32 + b) * 512 + u0 + j] = h;
    if (s == 127) hcat[b * 1024 + d * 512 + u0 + j] = h;  // buf 0
  }
}

// ---------------- K_cell: one decoder LSTM step (both dirs) ----------------
__global__ __launch_bounds__(NT) void k_cell(
    const int* __restrict__ tgt, const float* __restrict__ dec_emb,
    const float* __restrict__ dwih_f, const float* __restrict__ dwhh_f,
    const float* __restrict__ dbih_f, const float* __restrict__ dbhh_f,
    const float* __restrict__ dwih_r, const float* __restrict__ dwhh_r,
    const float* __restrict__ dbih_r, const float* __restrict__ dbhh_r,
    float* __restrict__ hcat, float* __restrict__ c_st,
    const unsigned long long* __restrict__ amax, int t) {
  extern __shared__ float smem[];
  const int tid = threadIdx.x;
  const int bid = blockIdx.x;
  const int d  = bid >> 7;
  const int u0 = (bid & 127) << 2;
  const int p = t & 1;

  float* xhL = smem;               // [32][XSTR]
  float* gLd = smem + 32 * XSTR;   // [32*16]

  const int rgD = tid >> 7;
  const int bpD = (tid >> 5) & 3;
  const int ksD = tid & 31;
  const int r0D = rgD * 2, r1D = r0D + 1;
  const int growD0 = (r0D & 3) * 512 + u0 + (r0D >> 2);
  const int growD1 = (r1D & 3) * 512 + u0 + (r1D >> 2);

  const float* dwih = d ? dwih_r : dwih_f;
  const float* dwhh = d ? dwhh_r : dwhh_f;
  const float* dbih = d ? dbih_r : dbih_f;
  const float* dbhh = d ? dbhh_r : dbhh_f;

  {
    int b = tid >> 5, i = tid & 31;
    int tok;
    if (t == 0) {
      tok = tgt[b * 64];
    } else {
      unsigned long long kv = amax[(t - 1) * 32 + b];
      tok = (int)(0xFFFFFFFFu - (unsigned)(kv & 0xFFFFFFFFull));
    }
    const float* xr = dec_emb + (size_t)tok * 512;
    const float* hr = hcat + (size_t)p * 32768 + b * 1024 + d * 512;
#pragma unroll
    for (int q = 0; q < 4; ++q) {
      int k = (i + 32 * q) * 4;
      float4 v = *(const float4*)(xr + k);
      int pc = k + ((k >> 5) << 2);
      *(float4*)(xhL + b * XSTR + pc) = v;
    }
#pragma unroll
    for (int q = 0; q < 4; ++q) {
      int k = (i + 32 * q) * 4;
      float4 v = *(const float4*)(hr + k);
      int c2 = 512 + k;
      int pc = c2 + ((c2 >> 5) << 2);
      *(float4*)(xhL + b * XSTR + pc) = v;
    }
  }
  float4 wA[8], wB[8];
  {
    const float* s0p = (ksD < 16) ? (dwih + (size_t)growD0 * 512 + ksD * 32)
                                  : (dwhh + (size_t)growD0 * 512 + (ksD - 16) * 32);
    const float* s1p = (ksD < 16) ? (dwih + (size_t)growD1 * 512 + ksD * 32)
                                  : (dwhh + (size_t)growD1 * 512 + (ksD - 16) * 32);
#pragma unroll
    for (int i4 = 0; i4 < 8; ++i4) {
      wA[i4] = *(const float4*)(s0p + i4 * 4);
      wB[i4] = *(const float4*)(s1p + i4 * 4);
    }
  }
  const float biasA = dbih[growD0] + dbhh[growD0];
  const float biasB = dbih[growD1] + dbhh[growD1];
  __syncthreads();
  for (int gi = 0; gi < 8; ++gi) {
    int b = bpD * 8 + gi;
    const float* hb = xhL + b * XSTR + ksD * 36;
    float4 a0 = {0, 0, 0, 0}, a1 = {0, 0, 0, 0};
#pragma unroll
    for (int i4 = 0; i4 < 8; ++i4) {
      float4 h4 = *(const float4*)(hb + i4 * 4);
      fma4(wA[i4], h4, a0);
      fma4(wB[i4], h4, a1);
    }
    float s0 = hsum4(a0), s1 = hsum4(a1);
#pragma unroll
    for (int m = 1; m <= 16; m <<= 1) {
      s0 += __shfl_xor(s0, m, 64);
      s1 += __shfl_xor(s1, m, 64);
    }
    if (ksD == 0) {
      gLd[b * 16 + r0D] = s0 + biasA;
      gLd[b * 16 + r1D] = s1 + biasB;
    }
  }
  __syncthreads();
  if (tid < 128) {
    int b = tid & 31, j = tid >> 5;
    float g_i = gLd[b * 16 + (j << 2) + 0];
    float g_f = gLd[b * 16 + (j << 2) + 1];
    float g_g = gLd[b * 16 + (j << 2) + 2];
    float g_o = gLd[b * 16 + (j << 2) + 3];
    float c = c_st[(d * 32 + b) * 512 + u0 + j];
    c = sigm(g_f) * c + sigm(g_i) * tanhf(g_g);
    float h = sigm(g_o) * tanhf(c);
    c_st[(d * 32 + b) * 512 + u0 + j] = c;
    hcat[(size_t)(p ^ 1) * 32768 + b * 1024 + d * 512 + u0 + j] = h;
  }
}

// ---------------- K_cls v16: kc8/bg8, 2 passes, unroll 4 ----------------
// grid 256 (one block per row-group: 125 rows x 32 b x full K).
// lane = (kc[0,8) x bg[0,8)): w-loads 128B distinct/instr (NT); lane's
// batches b = bg + 8j (j<4). Wave owns 8 rows as 2 passes of 4 rows;
// acc[4r][4j]=16 regs; kc-butterfly(1,2,4) = allreduce; writer lane kc==r.
__global__ __launch_bounds__(NT) void k_cls(
    const float* __restrict__ cls_w, const float* __restrict__ cls_b,
    const float* __restrict__ hcat, unsigned long long* __restrict__ amax,
    float* __restrict__ out, int t) {
  extern __shared__ float smem[];
  const int tid = threadIdx.x;
  const int g = blockIdx.x;
  const int p = t & 1;

  // LDS: cH float4[32][257] floats [0,32896); oL [32][126] floats [32896,36928);
  //      amaxL u64[32] at float 36928 (bytes 147712..147968)
  float* oL = smem + 32896;
  unsigned long long* amaxL = (unsigned long long*)(smem + 36928);

  {  // stage full h into padded cH; zero amaxL
    const float4* hr4 = (const float4*)(hcat + (size_t)(p ^ 1) * 32768);
    float4* cH4w = (float4*)smem;
#pragma unroll
    for (int q = 0; q < 8; ++q) {
      int f = tid + q * 1024;        // [0,8192)
      int b = f >> 8, k4 = f & 255;
      cH4w[b * 257 + k4] = hr4[f];
    }
    if (tid < 32) amaxL[tid] = 0ull;
  }
  __syncthreads();
  {
    const int lane = tid & 63;
    const int widu = __builtin_amdgcn_readfirstlane(tid >> 6);
    const int kc = lane & 7;          // k-chunk [0,8): 128B coalesced w-loads
    const int bg = lane >> 3;         // batch-class [0,8): b = bg + 8j
    const float4* cH4 = (const float4*)smem;

    unsigned long long bk[4];
#pragma unroll
    for (int j = 0; j < 4; ++j) bk[j] = 0ull;

#pragma unroll
    for (int pass = 0; pass < 2; ++pass) {
      const int lr0 = widu * 8 + pass * 4;   // rows lr0..lr0+3 (up to 127)
      const float* wr0 = cls_w + (size_t)(g * 125 + (lr0 + 0 > 124 ? 124 : lr0 + 0)) * 1024;
      const float* wr1 = cls_w + (size_t)(g * 125 + (lr0 + 1 > 124 ? 124 : lr0 + 1)) * 1024;
      const float* wr2 = cls_w + (size_t)(g * 125 + (lr0 + 2 > 124 ? 124 : lr0 + 2)) * 1024;
      const float* wr3 = cls_w + (size_t)(g * 125 + (lr0 + 3 > 124 ? 124 : lr0 + 3)) * 1024;

      float acc[16];   // acc[r*4 + j]
#pragma unroll
      for (int i = 0; i < 16; ++i) acc[i] = 0.f;

#pragma unroll 4
      for (int q = 0; q < 32; ++q) {
        const int ko = q * 32 + kc * 4;      // 8 kc lanes cover 128B contiguous
        f32x4 w0 = __builtin_nontemporal_load((const f32x4*)(wr0 + ko));
        f32x4 w1 = __builtin_nontemporal_load((const f32x4*)(wr1 + ko));
        f32x4 w2 = __builtin_nontemporal_load((const f32x4*)(wr2 + ko));
        f32x4 w3 = __builtin_nontemporal_load((const f32x4*)(wr3 + ko));
#pragma unroll
        for (int j = 0; j < 4; ++j) {
          float4 h4 = cH4[(bg + 8 * j) * 257 + q * 8 + kc];
          acc[0 * 4 + j] = dot4v(w0, h4, acc[0 * 4 + j]);
          acc[1 * 4 + j] = dot4v(w1, h4, acc[1 * 4 + j]);
          acc[2 * 4 + j] = dot4v(w2, h4, acc[2 * 4 + j]);
          acc[3 * 4 + j] = dot4v(w3, h4, acc[3 * 4 + j]);
        }
      }

      // butterfly over the 8 kc lanes = allreduce (every lane gets full sums)
#pragma unroll
      for (int i = 0; i < 16; ++i) {
        acc[i] += __shfl_xor(acc[i], 1, 64);
        acc[i] += __shfl_xor(acc[i], 2, 64);
        acc[i] += __shfl_xor(acc[i], 4, 64);
      }

#pragma unroll
      for (int r = 0; r < 4; ++r) {
        const int lr = lr0 + r;
        const int lrc = lr > 124 ? 124 : lr;
        const int vr = g * 125 + lrc;
        const float cb = cls_b[vr];
#pragma unroll
        for (int j = 0; j < 4; ++j) {
          const float lg = acc[r * 4 + j] + cb;
          const int b = bg + 8 * j;
          if (kc == r && lr < 125) oL[b * 126 + lr] = lg;
          if (lr < 125) {
            unsigned long long k = lgkey(lg, vr);
            bk[j] = k > bk[j] ? k : bk[j];
          }
        }
      }
    }
    if (kc == 0) {
#pragma unroll
      for (int j = 0; j < 4; ++j) atomicMax(&amaxL[bg + 8 * j], bk[j]);
    }
  }
  __syncthreads();
  // coalesced logit writeback (non-temporal) + global argmax merge
#pragma unroll
  for (int it = 0; it < 4; ++it) {
    int idx = tid + it * 1024;            // [0,4096)
    int b = idx >> 7, j = idx & 127;
    if (j < 125)
      __builtin_nontemporal_store(oL[b * 126 + j],
          &out[((size_t)b * 64 + (t + 1)) * 32000 + g * 125 + j]);
  }
  if (tid < 32) atomicMax(&amax[t * 32 + tid], amaxL[tid]);
}

extern "C" void kernel_launch(void* const* d_in, const int* in_sizes, int n_in,
                              void* d_out, int out_size, void* d_ws, size_t ws_size,
                              hipStream_t stream) {
  (void)in_sizes; (void)n_in; (void)out_size; (void)ws_size;
  const int*   src     = (const int*)d_in[0];
  const int*   tgt     = (const int*)d_in[1];
  const float* enc_emb = (const float*)d_in[2];
  const float* dec_emb = (const float*)d_in[3];
  const float* ewih_f  = (const float*)d_in[4];
  const float* ewhh_f  = (const float*)d_in[5];
  const float* ebih_f  = (const float*)d_in[6];
  const float* ebhh_f  = (const float*)d_in[7];
  const float* ewih_r  = (const float*)d_in[8];
  const float* ewhh_r  = (const float*)d_in[9];
  const float* ebih_r  = (const float*)d_in[10];
  const float* ebhh_r  = (const float*)d_in[11];
  const float* dwih_f  = (const float*)d_in[12];
  const float* dwhh_f  = (const float*)d_in[13];
  const float* dbih_f  = (const float*)d_in[14];
  const float* dbhh_f  = (const float*)d_in[15];
  const float* dwih_r  = (const float*)d_in[16];
  const float* dwhh_r  = (const float*)d_in[17];
  const float* dbih_r  = (const float*)d_in[18];
  const float* dbhh_r  = (const float*)d_in[19];
  const float* cls_w   = (const float*)d_in[20];
  const float* cls_b   = (const float*)d_in[21];

  char* ws = (char*)d_ws;
  unsigned long long* amax = (unsigned long long*)(ws + OFF_AMAX);
  float* Xg                = (float*)(ws + OFF_XG);
  float* h_enc             = (float*)(ws + OFF_HENC);
  float* hcat              = (float*)(ws + OFF_HCAT);
  float* c_st              = (float*)(ws + OFF_CST);
  float* out               = (float*)d_out;

  // reset argmax slots (monotone atomicMax needs zeros each call)
  hipMemsetAsync(d_ws, 0, OFF_XG, stream);

  hipFuncSetAttribute((const void*)k_xg,
                      hipFuncAttributeMaxDynamicSharedMemorySize, LDS_ENC);
  hipFuncSetAttribute((const void*)k_enc,
                      hipFuncAttributeMaxDynamicSharedMemorySize, LDS_ENC);
  hipFuncSetAttribute((const void*)k_cell,
                      hipFuncAttributeMaxDynamicSharedMemorySize, LDS_CELL);
  hipFuncSetAttribute((const void*)k_cls,
                      hipFuncAttributeMaxDynamicSharedMemorySize, LDS_CLS);

  hipLaunchKernelGGL(k_xg, dim3(NBLK), dim3(NT), LDS_ENC, stream,
                     src, enc_emb, ewih_f, ebih_f, ebhh_f,
                     ewih_r, ebih_r, ebhh_r, Xg, h_enc, out);

  for (int s = 0; s < 128; ++s) {
    hipLaunchKernelGGL(k_enc, dim3(NBLK), dim3(NT), LDS_ENC, stream,
                       ewhh_f, ewhh_r, Xg, h_enc, hcat, c_st, s);
  }

  for (int t = 0; t < 63; ++t) {
    hipLaunchKernelGGL(k_cell, dim3(NBLK), dim3(NT), LDS_CELL, stream,
                       tgt, dec_emb,
                       dwih_f, dwhh_f, dbih_f, dbhh_f,
                       dwih_r, dwhh_r, dbih_r, dbhh_r,
                       hcat, c_st, amax, t);
    hipLaunchKernelGGL(k_cls, dim3(NBLK), dim3(NT), LDS_CLS, stream,
                       cls_w, cls_b, hcat, amax, out, t);
  }
}

// Round 17
// 6277.541 us; speedup vs baseline: 1.4298x; 1.1261x over previous
//
#include <hip/hip_runtime.h>
#include <stdint.h>

// Seq2Seq (bi-LSTM encoder + greedy LSTM decoder), MI355X gfx950.
// v17: v16 with CACHING weight loads (drop the NT hint on cls_w reads).
//   R16 post-mortem: unroll4 neutral -> not latency-bound. NT-history audit:
//   the config that lets the 256MB Infinity Cache retain cls_w was never
//   tested: dedup'd 131MB/step read set (v12+) + NT logit stores (v10+)
//   + REGULAR loads. R6's non-retention had write-allocate churn (258MB of
//   regular stores); v10 had a 262MB/step read set (2x dup > L3). Now:
//   131MB < 256MB, writes NT'd out of allocation -> steps 2..63 should hit
//   L3 (~17TB/s) -> k_cls ~20-25us/step. Only change: dot4v loads are plain
//   dereferences. Everything else byte-identical to v16.
//
// B=32 S=128 T=64 V=32000 E=512 H=512 (4H=2048 gates per cell)

#define NT 1024
#define NBLK 256

constexpr int HSTR = 580;    // enc h-stage LDS row stride (512 + pad, %32==4)
constexpr int XSTR = 1156;   // dec [x|h]-stage stride (1024 + pad, %32==4)
constexpr unsigned LDS_ENC = 78336;    // (32*580 + 512 + 512) floats
constexpr unsigned LDS_CELL = 150016;  // (32*1156 + 512) floats
constexpr unsigned LDS_CLS = 147968;   // cH[32][257]f4 + oL[32][126] + amaxL[32]

// workspace layout (bytes)
constexpr size_t OFF_AMAX  = 0;                     // 63*32 u64 = 16128
constexpr size_t OFF_XG    = 17408;                 // 256*128*32*16 f32 = 67108864
constexpr size_t OFF_HENC  = OFF_XG + 67108864ULL;  // 2buf*2dir*32*512 f32 = 262144
constexpr size_t OFF_HCAT  = OFF_HENC + 262144ULL;  // 2buf*32*1024 f32 = 262144
constexpr size_t OFF_CST   = OFF_HCAT + 262144ULL;  // 2dir*32*512 f32 = 131072

typedef float f32x4 __attribute__((ext_vector_type(4)));

__device__ __forceinline__ float sigm(float x) {
  if (x >= 0.f) return 1.f / (1.f + expf(-x));
  float e = expf(x);
  return e / (1.f + e);
}

__device__ __forceinline__ void fma4(const float4& w, const float4& h, float4& a) {
  a.x = fmaf(w.x, h.x, a.x);
  a.y = fmaf(w.y, h.y, a.y);
  a.z = fmaf(w.z, h.z, a.z);
  a.w = fmaf(w.w, h.w, a.w);
}

__device__ __forceinline__ float hsum4(const float4& a) {
  return (a.x + a.y) + (a.z + a.w);
}

__device__ __forceinline__ float dot4(const float4& w, const float4& h, float acc) {
  return fmaf(w.x, h.x, fmaf(w.y, h.y, fmaf(w.z, h.z, fmaf(w.w, h.w, acc))));
}

__device__ __forceinline__ float dot4v(const f32x4& w, const float4& h, float acc) {
  return fmaf(w.x, h.x, fmaf(w.y, h.y, fmaf(w.z, h.z, fmaf(w.w, h.w, acc))));
}

__device__ __forceinline__ unsigned long long lgkey(float lg, int vr) {
  unsigned u = __float_as_uint(lg);
  u = (u & 0x80000000u) ? ~u : (u | 0x80000000u);
  return ((unsigned long long)u << 32) | (0xFFFFFFFFu - (unsigned)vr);
}

// ---------------- K0: Xg = emb(src) @ wih^T + bih + bhh; init h_enc, out ----
__global__ __launch_bounds__(NT) void k_xg(
    const int* __restrict__ src, const float* __restrict__ enc_emb,
    const float* __restrict__ ewih_f, const float* __restrict__ ebih_f,
    const float* __restrict__ ebhh_f,
    const float* __restrict__ ewih_r, const float* __restrict__ ebih_r,
    const float* __restrict__ ebhh_r,
    float* __restrict__ Xg, float* __restrict__ h_enc, float* __restrict__ out) {
  extern __shared__ float smem[];
  const int tid = threadIdx.x;
  const int bid = blockIdx.x;
  const int d  = bid >> 7;
  const int u0 = (bid & 127) << 2;

  float* hL  = smem;               // [32][HSTR]

  const int rgE = tid >> 7;
  const int bpE = (tid >> 4) & 7;
  const int ksE = tid & 15;
  const int r0E = rgE * 2, r1E = r0E + 1;
  const int growE0 = (r0E & 3) * 512 + u0 + (r0E >> 2);
  const int growE1 = (r1E & 3) * 512 + u0 + (r1E >> 2);

  const float* ewih = d ? ewih_r : ewih_f;
  const float* ebih = d ? ebih_r : ebih_f;
  const float* ebhh = d ? ebhh_r : ebhh_f;

  float4 wA[8], wB[8];
#pragma unroll
  for (int i4 = 0; i4 < 8; ++i4) {
    wA[i4] = *(const float4*)(ewih + (size_t)growE0 * 512 + ksE * 32 + i4 * 4);
    wB[i4] = *(const float4*)(ewih + (size_t)growE1 * 512 + ksE * 32 + i4 * 4);
  }
  const float biasA = ebih[growE0] + ebhh[growE0];
  const float biasB = ebih[growE1] + ebhh[growE1];

  for (int t = 0; t < 128; ++t) {
    {
      int b = tid >> 5, i = tid & 31;
      int tok = src[b * 128 + t];
      const float* row = enc_emb + (size_t)tok * 512;
#pragma unroll
      for (int q = 0; q < 4; ++q) {
        int k = (i + 32 * q) * 4;
        float4 v = *(const float4*)(row + k);
        int pc = k + ((k >> 5) << 2);
        *(float4*)(hL + b * HSTR + pc) = v;
      }
    }
    __syncthreads();
    for (int gi = 0; gi < 4; ++gi) {
      int b = bpE * 4 + gi;
      const float* hb = hL + b * HSTR + ksE * 36;
      float4 a0 = {0, 0, 0, 0}, a1 = {0, 0, 0, 0};
#pragma unroll
      for (int i4 = 0; i4 < 8; ++i4) {
        float4 h4 = *(const float4*)(hb + i4 * 4);
        fma4(wA[i4], h4, a0);
        fma4(wB[i4], h4, a1);
      }
      float s0 = hsum4(a0), s1 = hsum4(a1);
#pragma unroll
      for (int m = 1; m <= 8; m <<= 1) {
        s0 += __shfl_xor(s0, m, 64);
        s1 += __shfl_xor(s1, m, 64);
      }
      if (ksE == 0) {
        float* xgp = Xg + ((size_t)bid << 16) + t * 512 + b * 16;
        xgp[r0E] = s0 + biasA;
        xgp[r1E] = s1 + biasB;
      }
    }
    __syncthreads();
  }

  if (tid < 128) {
    int b = tid & 31, j = tid >> 5;
    h_enc[((0 * 2 + d) * 32 + b) * 512 + u0 + j] = 0.f;
  }
  for (int i = tid; i < 4000; i += NT) {
    int b = i & 31, vv = i >> 5;  // vv < 125
    __builtin_nontemporal_store(0.f,
        &out[(size_t)b * 64 * 32000 + bid * 125 + vv]);
  }
}

// ---------------- K_enc: one bi-LSTM encoder time step ----------------
__global__ __launch_bounds__(NT) void k_enc(
    const float* __restrict__ ewhh_f, const float* __restrict__ ewhh_r,
    const float* __restrict__ Xg, float* __restrict__ h_enc,
    float* __restrict__ hcat, float* __restrict__ c_st, int s) {
  extern __shared__ float smem[];
  const int tid = threadIdx.x;
  const int bid = blockIdx.x;
  const int d  = bid >> 7;
  const int u0 = (bid & 127) << 2;
  const int cur = s & 1;
  const int td = d ? (127 - s) : s;

  float* hL  = smem;               // [32][HSTR]
  float* XgL = smem + 32 * HSTR;   // [32*16]
  float* gL  = XgL + 512;          // [32*16]

  const int rgE = tid >> 7;
  const int bpE = (tid >> 4) & 7;
  const int ksE = tid & 15;
  const int r0E = rgE * 2, r1E = r0E + 1;
  const int growE0 = (r0E & 3) * 512 + u0 + (r0E >> 2);
  const int growE1 = (r1E & 3) * 512 + u0 + (r1E >> 2);

  const float* ewhh = d ? ewhh_r : ewhh_f;

  float4 wA[8], wB[8];
#pragma unroll
  for (int i4 = 0; i4 < 8; ++i4) {
    wA[i4] = *(const float4*)(ewhh + (size_t)growE0 * 512 + ksE * 32 + i4 * 4);
    wB[i4] = *(const float4*)(ewhh + (size_t)growE1 * 512 + ksE * 32 + i4 * 4);
  }

  {
    int b = tid >> 5, i = tid & 31;
    const float* hr = h_enc + ((size_t)(cur * 2 + d) * 32 + b) * 512;
#pragma unroll
    for (int q = 0; q < 4; ++q) {
      int k = (i + 32 * q) * 4;
      float4 v = *(const float4*)(hr + k);
      int pc = k + ((k >> 5) << 2);
      *(float4*)(hL + b * HSTR + pc) = v;
    }
    if (tid < 128) {
      ((float4*)XgL)[tid] =
          *(const float4*)(Xg + ((size_t)bid << 16) + td * 512 + tid * 4);
    }
  }
  __syncthreads();
  for (int gi = 0; gi < 4; ++gi) {
    int b = bpE * 4 + gi;
    const float* hb = hL + b * HSTR + ksE * 36;
    float4 a0 = {0, 0, 0, 0}, a1 = {0, 0, 0, 0};
#pragma unroll
    for (int i4 = 0; i4 < 8; ++i4) {
      float4 h4 = *(const float4*)(hb + i4 * 4);
      fma4(wA[i4], h4, a0);
      fma4(wB[i4], h4, a1);
    }
    float s0 = hsum4(a0), s1 = hsum4(a1);
#pragma unroll
    for (int m = 1; m <= 8; m <<= 1) {
      s0 += __shfl_xor(s0, m, 64);
      s1 += __shfl_xor(s1, m, 64);
    }
    if (ksE == 0) {
      gL[b * 16 + r0E] = s0 + XgL[b * 16 + r0E];
      gL[b * 16 + r1E] = s1 + XgL[b * 16 + r1E];
    }
  }
  __syncthreads();
  if (tid < 128) {
    int b = tid & 31, j = tid >> 5;
    float g_i = gL[b * 16 + (j << 2) + 0];
    float g_f = gL[b * 16 + (j << 2) + 1];
    float g_g = gL[b * 16 + (j << 2) + 2];
    float g_o = gL[b * 16 + (j << 2) + 3];
    float c = (s == 0) ? 0.f : c_st[(d * 32 + b) * 512 + u0 + j];
    c = sigm(g_f) * c + sigm(g_i) * tanhf(g_g);
    float h = sigm(g_o) * tanhf(c);
    c_st[(d * 32 + b) * 512 + u0 + j] = c;
    h_enc[(((cur ^ 1) * 2 + d) * 32 + b) * 512 + u0 + j] = h;
    if (s == 127) hcat[b * 1024 + d * 512 + u0 + j] = h;  // buf 0
  }
}

// ---------------- K_cell: one decoder LSTM step (both dirs) ----------------
__global__ __launch_bounds__(NT) void k_cell(
    const int* __restrict__ tgt, const float* __restrict__ dec_emb,
    const float* __restrict__ dwih_f, const float* __restrict__ dwhh_f,
    const float* __restrict__ dbih_f, const float* __restrict__ dbhh_f,
    const float* __restrict__ dwih_r, const float* __restrict__ dwhh_r,
    const float* __restrict__ dbih_r, const float* __restrict__ dbhh_r,
    float* __restrict__ hcat, float* __restrict__ c_st,
    const unsigned long long* __restrict__ amax, int t) {
  extern __shared__ float smem[];
  const int tid = threadIdx.x;
  const int bid = blockIdx.x;
  const int d  = bid >> 7;
  const int u0 = (bid & 127) << 2;
  const int p = t & 1;

  float* xhL = smem;               // [32][XSTR]
  float* gLd = smem + 32 * XSTR;   // [32*16]

  const int rgD = tid >> 7;
  const int bpD = (tid >> 5) & 3;
  const int ksD = tid & 31;
  const int r0D = rgD * 2, r1D = r0D + 1;
  const int growD0 = (r0D & 3) * 512 + u0 + (r0D >> 2);
  const int growD1 = (r1D & 3) * 512 + u0 + (r1D >> 2);

  const float* dwih = d ? dwih_r : dwih_f;
  const float* dwhh = d ? dwhh_r : dwhh_f;
  const float* dbih = d ? dbih_r : dbih_f;
  const float* dbhh = d ? dbhh_r : dbhh_f;

  {
    int b = tid >> 5, i = tid & 31;
    int tok;
    if (t == 0) {
      tok = tgt[b * 64];
    } else {
      unsigned long long kv = amax[(t - 1) * 32 + b];
      tok = (int)(0xFFFFFFFFu - (unsigned)(kv & 0xFFFFFFFFull));
    }
    const float* xr = dec_emb + (size_t)tok * 512;
    const float* hr = hcat + (size_t)p * 32768 + b * 1024 + d * 512;
#pragma unroll
    for (int q = 0; q < 4; ++q) {
      int k = (i + 32 * q) * 4;
      float4 v = *(const float4*)(xr + k);
      int pc = k + ((k >> 5) << 2);
      *(float4*)(xhL + b * XSTR + pc) = v;
    }
#pragma unroll
    for (int q = 0; q < 4; ++q) {
      int k = (i + 32 * q) * 4;
      float4 v = *(const float4*)(hr + k);
      int c2 = 512 + k;
      int pc = c2 + ((c2 >> 5) << 2);
      *(float4*)(xhL + b * XSTR + pc) = v;
    }
  }
  float4 wA[8], wB[8];
  {
    const float* s0p = (ksD < 16) ? (dwih + (size_t)growD0 * 512 + ksD * 32)
                                  : (dwhh + (size_t)growD0 * 512 + (ksD - 16) * 32);
    const float* s1p = (ksD < 16) ? (dwih + (size_t)growD1 * 512 + ksD * 32)
                                  : (dwhh + (size_t)growD1 * 512 + (ksD - 16) * 32);
#pragma unroll
    for (int i4 = 0; i4 < 8; ++i4) {
      wA[i4] = *(const float4*)(s0p + i4 * 4);
      wB[i4] = *(const float4*)(s1p + i4 * 4);
    }
  }
  const float biasA = dbih[growD0] + dbhh[growD0];
  const float biasB = dbih[growD1] + dbhh[growD1];
  __syncthreads();
  for (int gi = 0; gi < 8; ++gi) {
    int b = bpD * 8 + gi;
    const float* hb = xhL + b * XSTR + ksD * 36;
    float4 a0 = {0, 0, 0, 0}, a1 = {0, 0, 0, 0};
#pragma unroll
    for (int i4 = 0; i4 < 8; ++i4) {
      float4 h4 = *(const float4*)(hb + i4 * 4);
      fma4(wA[i4], h4, a0);
      fma4(wB[i4], h4, a1);
    }
    float s0 = hsum4(a0), s1 = hsum4(a1);
#pragma unroll
    for (int m = 1; m <= 16; m <<= 1) {
      s0 += __shfl_xor(s0, m, 64);
      s1 += __shfl_xor(s1, m, 64);
    }
    if (ksD == 0) {
      gLd[b * 16 + r0D] = s0 + biasA;
      gLd[b * 16 + r1D] = s1 + biasB;
    }
  }
  __syncthreads();
  if (tid < 128) {
    int b = tid & 31, j = tid >> 5;
    float g_i = gLd[b * 16 + (j << 2) + 0];
    float g_f = gLd[b * 16 + (j << 2) + 1];
    float g_g = gLd[b * 16 + (j << 2) + 2];
    float g_o = gLd[b * 16 + (j << 2) + 3];
    float c = c_st[(d * 32 + b) * 512 + u0 + j];
    c = sigm(g_f) * c + sigm(g_i) * tanhf(g_g);
    float h = sigm(g_o) * tanhf(c);
    c_st[(d * 32 + b) * 512 + u0 + j] = c;
    hcat[(size_t)(p ^ 1) * 32768 + b * 1024 + d * 512 + u0 + j] = h;
  }
}

// ---------------- K_cls v17: kc8/bg8, 2 passes, CACHING w-loads ----------------
// grid 256 (one block per row-group: 125 rows x 32 b x full K).
// lane = (kc[0,8) x bg[0,8)): w-loads 128B distinct/instr (cached: L3 can
// retain the dedup'd 131MB read set across steps); lane's batches
// b = bg + 8j (j<4). Wave owns 8 rows as 2 passes of 4 rows;
// acc[4r][4j]=16 regs; kc-butterfly(1,2,4) = allreduce; writer lane kc==r.
__global__ __launch_bounds__(NT) void k_cls(
    const float* __restrict__ cls_w, const float* __restrict__ cls_b,
    const float* __restrict__ hcat, unsigned long long* __restrict__ amax,
    float* __restrict__ out, int t) {
  extern __shared__ float smem[];
  const int tid = threadIdx.x;
  const int g = blockIdx.x;
  const int p = t & 1;

  // LDS: cH float4[32][257] floats [0,32896); oL [32][126] floats [32896,36928);
  //      amaxL u64[32] at float 36928 (bytes 147712..147968)
  float* oL = smem + 32896;
  unsigned long long* amaxL = (unsigned long long*)(smem + 36928);

  {  // stage full h into padded cH; zero amaxL
    const float4* hr4 = (const float4*)(hcat + (size_t)(p ^ 1) * 32768);
    float4* cH4w = (float4*)smem;
#pragma unroll
    for (int q = 0; q < 8; ++q) {
      int f = tid + q * 1024;        // [0,8192)
      int b = f >> 8, k4 = f & 255;
      cH4w[b * 257 + k4] = hr4[f];
    }
    if (tid < 32) amaxL[tid] = 0ull;
  }
  __syncthreads();
  {
    const int lane = tid & 63;
    const int widu = __builtin_amdgcn_readfirstlane(tid >> 6);
    const int kc = lane & 7;          // k-chunk [0,8): 128B coalesced w-loads
    const int bg = lane >> 3;         // batch-class [0,8): b = bg + 8j
    const float4* cH4 = (const float4*)smem;

    unsigned long long bk[4];
#pragma unroll
    for (int j = 0; j < 4; ++j) bk[j] = 0ull;

#pragma unroll
    for (int pass = 0; pass < 2; ++pass) {
      const int lr0 = widu * 8 + pass * 4;   // rows lr0..lr0+3 (up to 127)
      const float* wr0 = cls_w + (size_t)(g * 125 + (lr0 + 0 > 124 ? 124 : lr0 + 0)) * 1024;
      const float* wr1 = cls_w + (size_t)(g * 125 + (lr0 + 1 > 124 ? 124 : lr0 + 1)) * 1024;
      const float* wr2 = cls_w + (size_t)(g * 125 + (lr0 + 2 > 124 ? 124 : lr0 + 2)) * 1024;
      const float* wr3 = cls_w + (size_t)(g * 125 + (lr0 + 3 > 124 ? 124 : lr0 + 3)) * 1024;

      float acc[16];   // acc[r*4 + j]
#pragma unroll
      for (int i = 0; i < 16; ++i) acc[i] = 0.f;

#pragma unroll 4
      for (int q = 0; q < 32; ++q) {
        const int ko = q * 32 + kc * 4;      // 8 kc lanes cover 128B contiguous
        f32x4 w0 = *(const f32x4*)(wr0 + ko);
        f32x4 w1 = *(const f32x4*)(wr1 + ko);
        f32x4 w2 = *(const f32x4*)(wr2 + ko);
        f32x4 w3 = *(const f32x4*)(wr3 + ko);
#pragma unroll
        for (int j = 0; j < 4; ++j) {
          float4 h4 = cH4[(bg + 8 * j) * 257 + q * 8 + kc];
          acc[0 * 4 + j] = dot4v(w0, h4, acc[0 * 4 + j]);
          acc[1 * 4 + j] = dot4v(w1, h4, acc[1 * 4 + j]);
          acc[2 * 4 + j] = dot4v(w2, h4, acc[2 * 4 + j]);
          acc[3 * 4 + j] = dot4v(w3, h4, acc[3 * 4 + j]);
        }
      }

      // butterfly over the 8 kc lanes = allreduce (every lane gets full sums)
#pragma unroll
      for (int i = 0; i < 16; ++i) {
        acc[i] += __shfl_xor(acc[i], 1, 64);
        acc[i] += __shfl_xor(acc[i], 2, 64);
        acc[i] += __shfl_xor(acc[i], 4, 64);
      }

#pragma unroll
      for (int r = 0; r < 4; ++r) {
        const int lr = lr0 + r;
        const int lrc = lr > 124 ? 124 : lr;
        const int vr = g * 125 + lrc;
        const float cb = cls_b[vr];
#pragma unroll
        for (int j = 0; j < 4; ++j) {
          const float lg = acc[r * 4 + j] + cb;
          const int b = bg + 8 * j;
          if (kc == r && lr < 125) oL[b * 126 + lr] = lg;
          if (lr < 125) {
            unsigned long long k = lgkey(lg, vr);
            bk[j] = k > bk[j] ? k : bk[j];
          }
        }
      }
    }
    if (kc == 0) {
#pragma unroll
      for (int j = 0; j < 4; ++j) atomicMax(&amaxL[bg + 8 * j], bk[j]);
    }
  }
  __syncthreads();
  // coalesced logit writeback (non-temporal) + global argmax merge
#pragma unroll
  for (int it = 0; it < 4; ++it) {
    int idx = tid + it * 1024;            // [0,4096)
    int b = idx >> 7, j = idx & 127;
    if (j < 125)
      __builtin_nontemporal_store(oL[b * 126 + j],
          &out[((size_t)b * 64 + (t + 1)) * 32000 + g * 125 + j]);
  }
  if (tid < 32) atomicMax(&amax[t * 32 + tid], amaxL[tid]);
}

extern "C" void kernel_launch(void* const* d_in, const int* in_sizes, int n_in,
                              void* d_out, int out_size, void* d_ws, size_t ws_size,
                              hipStream_t stream) {
  (void)in_sizes; (void)n_in; (void)out_size; (void)ws_size;
  const int*   src     = (const int*)d_in[0];
  const int*   tgt     = (const int*)d_in[1];
  const float* enc_emb = (const float*)d_in[2];
  const float* dec_emb = (const float*)d_in[3];
  const float* ewih_f  = (const float*)d_in[4];
  const float* ewhh_f  = (const float*)d_in[5];
  const float* ebih_f  = (const float*)d_in[6];
  const float* ebhh_f  = (const float*)d_in[7];
  const float* ewih_r  = (const float*)d_in[8];
  const float* ewhh_r  = (const float*)d_in[9];
  const float* ebih_r  = (const float*)d_in[10];
  const float* ebhh_r  = (const float*)d_in[11];
  const float* dwih_f  = (const float*)d_in[12];
  const float* dwhh_f  = (const float*)d_in[13];
  const float* dbih_f  = (const float*)d_in[14];
  const float* dbhh_f  = (const float*)d_in[15];
  const float* dwih_r  = (const float*)d_in[16];
  const float* dwhh_r  = (const float*)d_in[17];
  const float* dbih_r  = (const float*)d_in[18];
  const float* dbhh_r  = (const float*)d_in[19];
  const float* cls_w   = (const float*)d_in[20];
  const float* cls_b   = (const float*)d_in[21];

  char* ws = (char*)d_ws;
  unsigned long long* amax = (unsigned long long*)(ws + OFF_AMAX);
  float* Xg                = (float*)(ws + OFF_XG);
  float* h_enc             = (float*)(ws + OFF_HENC);
  float* hcat              = (float*)(ws + OFF_HCAT);
  float* c_st              = (float*)(ws + OFF_CST);
  float* out               = (float*)d_out;

  // reset argmax slots (monotone atomicMax needs zeros each call)
  hipMemsetAsync(d_ws, 0, OFF_XG, stream);

  hipFuncSetAttribute((const void*)k_xg,
                      hipFuncAttributeMaxDynamicSharedMemorySize, LDS_ENC);
  hipFuncSetAttribute((const void*)k_enc,
                      hipFuncAttributeMaxDynamicSharedMemorySize, LDS_ENC);
  hipFuncSetAttribute((const void*)k_cell,
                      hipFuncAttributeMaxDynamicSharedMemorySize, LDS_CELL);
  hipFuncSetAttribute((const void*)k_cls,
                      hipFuncAttributeMaxDynamicSharedMemorySize, LDS_CLS);

  hipLaunchKernelGGL(k_xg, dim3(NBLK), dim3(NT), LDS_ENC, stream,
                     src, enc_emb, ewih_f, ebih_f, ebhh_f,
                     ewih_r, ebih_r, ebhh_r, Xg, h_enc, out);

  for (int s = 0; s < 128; ++s) {
    hipLaunchKernelGGL(k_enc, dim3(NBLK), dim3(NT), LDS_ENC, stream,
                       ewhh_f, ewhh_r, Xg, h_enc, hcat, c_st, s);
  }

  for (int t = 0; t < 63; ++t) {
    hipLaunchKernelGGL(k_cell, dim3(NBLK), dim3(NT), LDS_CELL, stream,
                       tgt, dec_emb,
                       dwih_f, dwhh_f, dbih_f, dbhh_f,
                       dwih_r, dwhh_r, dbih_r, dbhh_r,
                       hcat, c_st, amax, t);
    hipLaunchKernelGGL(k_cls, dim3(NBLK), dim3(NT), LDS_CLS, stream,
                       cls_w, cls_b, hcat, amax, out, t);
  }
}